// Round 5
// baseline (137.413 us; speedup 1.0000x reference)
//
#include <hip/hip_runtime.h>
#include <hip/hip_bf16.h>

// Non-backtracking random walk, 32 steps.
// out = [walks (steps+1,n) ; walk_edges (steps,n)] int32.
//
// R5: walker is bound by outstanding-miss capacity (R4: 2 chains/thread gave
// -12us). Push further:
//  (a) FOUR chains per thread (choices preloaded in two 16-step halves to cap
//      VGPRs) -> 12 independent gathers in flight per thread at each stall.
//  (b) 64B-aligned packed rows (16 u16 lo + u16 hbits + pad): all three
//      per-step loads hit ONE cache line (2nd/3rd are L1 hits), halving L2
//      request count vs the stride-36 layout.
// Pack kernel verifies uniform CSR (deg==16, offset==16v, ids<2^17); on
// violation walker takes a fully-general fallback.

#define DEG 16
#define CHAINS 4

__global__ void pack_check_kernel(const int* __restrict__ adj_nodes,
                                  const int* __restrict__ adj_offset,
                                  const int* __restrict__ degrees,
                                  int n,
                                  unsigned int* __restrict__ pk32,  // 16 u32 per row (64B)
                                  int* __restrict__ flag) {
    int v = blockIdx.x * blockDim.x + threadIdx.x;
    if (v >= n) return;

    bool bad = (degrees[v] != DEG) || (adj_offset[v] != v * DEG);

    const int* row = adj_nodes + (size_t)v * DEG;
    union { unsigned u32[8]; uint4 v4[2]; } p;
    unsigned hbits = 0;
#pragma unroll
    for (int j = 0; j < 8; ++j) {
        unsigned u0 = (unsigned)row[2 * j];
        unsigned u1 = (unsigned)row[2 * j + 1];
        if (u0 >= 131072u || u1 >= 131072u) bad = true;   // needs >17 bits
        p.u32[j] = (u0 & 0xffffu) | ((u1 & 0xffffu) << 16);
        hbits |= ((u0 >> 16) & 1u) << (2 * j);
        hbits |= ((u1 >> 16) & 1u) << (2 * j + 1);
    }
    unsigned int* dst = pk32 + (size_t)v * 16;   // 64B-aligned row
    ((uint4*)dst)[0] = p.v4[0];
    ((uint4*)dst)[1] = p.v4[1];
    dst[8] = hbits;                               // u16 hbits at r[16]

    if (bad) atomicOr(flag, 1);
}

template <int STEPS>
__global__ __launch_bounds__(64) void walker_fast4(
    const unsigned short* __restrict__ pk,   // 32 u16 per row (64B stride)
    const int* __restrict__ choices,
    int* __restrict__ out, int n, int h,
    const int* __restrict__ flag,
    const int* __restrict__ adj_nodes,
    const int* __restrict__ adj_offset,
    const int* __restrict__ degrees) {

    int t = blockIdx.x * blockDim.x + threadIdx.x;
    if (t >= h) return;

    int* walks      = out;                    // [STEPS+1, n]
    int* walk_edges = out + (STEPS + 1) * n;  // [STEPS, n]

    int  w[CHAINS], wsx[CHAINS];
    bool val[CHAINS];
#pragma unroll
    for (int c = 0; c < CHAINS; ++c) {
        w[c]   = t + c * h;
        val[c] = (w[c] < n);
        wsx[c] = val[c] ? w[c] : t;           // safe index for loads
        if (val[c]) __builtin_nontemporal_store(w[c], &walks[w[c]]);
    }

    if (*flag == 0) {
        // ---- fast path: uniform CSR deg=16, 64B rows, 4 chains/thread ----
        int prev[CHAINS], cur[CHAINS];
#pragma unroll
        for (int c = 0; c < CHAINS; ++c) { prev[c] = -1; cur[c] = wsx[c]; }

        static_assert(STEPS % 16 == 0, "");
#pragma unroll 1
        for (int half = 0; half < STEPS / 16; ++half) {
            int ch[CHAINS][16];
#pragma unroll
            for (int i = 0; i < 16; ++i)
#pragma unroll
                for (int c = 0; c < CHAINS; ++c)
                    ch[c][i] = __builtin_nontemporal_load(
                        &choices[(half * 16 + i) * n + wsx[c]]);

#pragma unroll
            for (int i = 0; i < 16; ++i) {
                int step = half * 16 + i;
                unsigned e[CHAINS], ae[CHAINS], l0[CHAINS], l1[CHAINS], hb[CHAINS];
#pragma unroll
                for (int c = 0; c < CHAINS; ++c) {
                    int chv = ch[c][i];
                    e[c]  = chv & (DEG - 1);
                    ae[c] = (e[c] + 1 + chv % (DEG - 1)) & (DEG - 1);
                    const unsigned short* r = pk + (unsigned)cur[c] * 32u;
                    l0[c] = r[e[c]];     // all three: same 64B line
                    l1[c] = r[ae[c]];
                    hb[c] = r[16];
                }
#pragma unroll
                for (int c = 0; c < CHAINS; ++c) {
                    int n0 = (int)(l0[c] | (((hb[c] >> e[c])  & 1u) << 16));
                    int n1 = (int)(l1[c] | (((hb[c] >> ae[c]) & 1u) << 16));
                    bool bt = (n0 == prev[c]);
                    int nw  = bt ? n1 : n0;
                    int ce  = (cur[c] << 4) + (int)(bt ? ae[c] : e[c]);
                    if (val[c]) {
                        __builtin_nontemporal_store(nw, &walks[(step + 1) * n + w[c]]);
                        __builtin_nontemporal_store(ce, &walk_edges[step * n + w[c]]);
                    }
                    prev[c] = cur[c];
                    cur[c]  = nw;
                }
            }
        }
    } else {
        // ---- general fallback ----
        for (int c = 0; c < CHAINS; ++c) {
            if (!val[c]) continue;
            int wk = w[c];
            int prev = -1, cur = wk;
            for (int i = 0; i < STEPS; ++i) {
                int chv = choices[i * n + wk];
                int deg = degrees[cur];
                int off = adj_offset[cur];
                int nb  = deg - 1 > 1 ? deg - 1 : 1;

                int ee     = chv % deg;
                int chosen = off + ee;
                int alt    = off + (ee + 1 + chv % nb) % deg;

                int nv0 = adj_nodes[chosen];
                int nv1 = adj_nodes[alt];

                bool bt = (nv0 == prev);
                int nw  = bt ? nv1 : nv0;
                walks[(i + 1) * n + wk] = nw;
                walk_edges[i * n + wk]  = bt ? alt : chosen;
                prev = cur;
                cur  = nw;
            }
        }
    }
}

__global__ __launch_bounds__(256) void walker_generic(
    const int* __restrict__ adj_nodes,
    const int* __restrict__ adj_offset,
    const int* __restrict__ degrees,
    const int* __restrict__ choices,
    int* __restrict__ out, int n, int steps) {

    int w = blockIdx.x * blockDim.x + threadIdx.x;
    if (w >= n) return;

    int* walks      = out;
    int* walk_edges = out + (steps + 1) * n;
    walks[w] = w;

    int prev = -1, cur = w;
    for (int i = 0; i < steps; ++i) {
        int chv = choices[i * n + w];
        int deg = degrees[cur];
        int off = adj_offset[cur];
        int nb  = deg - 1 > 1 ? deg - 1 : 1;

        int e      = chv % deg;
        int chosen = off + e;
        int alt    = off + (e + 1 + chv % nb) % deg;

        int nv0 = adj_nodes[chosen];
        int nv1 = adj_nodes[alt];

        bool bt = (nv0 == prev);
        int nw  = bt ? nv1 : nv0;
        walks[(i + 1) * n + w] = nw;
        walk_edges[i * n + w]  = bt ? alt : chosen;
        prev = cur;
        cur  = nw;
    }
}

extern "C" void kernel_launch(void* const* d_in, const int* in_sizes, int n_in,
                              void* d_out, int out_size, void* d_ws, size_t ws_size,
                              hipStream_t stream) {
    // inputs: 0=x (unused), 1=adj_nodes, 2=adj_offset, 3=degrees, 4=choices
    const int* adj_nodes  = (const int*)d_in[1];
    const int* adj_offset = (const int*)d_in[2];
    const int* degrees    = (const int*)d_in[3];
    const int* choices    = (const int*)d_in[4];
    int* out = (int*)d_out;

    int n     = in_sizes[2];
    int steps = in_sizes[4] / n;

    // ws layout: [0,4) flag | [64, 64+64n) packed 64B rows
    size_t pk_off = 64;
    size_t need   = pk_off + (size_t)n * 64;

    if (steps == 32 && ws_size >= need) {
        int* flag = (int*)d_ws;
        unsigned int*   pk32 = (unsigned int*)((char*)d_ws + pk_off);
        unsigned short* pk   = (unsigned short*)pk32;

        hipMemsetAsync(flag, 0, sizeof(int), stream);
        int pb = 256, pg = (n + pb - 1) / pb;
        pack_check_kernel<<<pg, pb, 0, stream>>>(adj_nodes, adj_offset, degrees,
                                                 n, pk32, flag);
        int h  = (n + CHAINS - 1) / CHAINS;
        int wb = 64, wg = (h + wb - 1) / wb;
        walker_fast4<32><<<wg, wb, 0, stream>>>(pk, choices, out, n, h, flag,
                                                adj_nodes, adj_offset, degrees);
    } else {
        int block = 256, grid = (n + block - 1) / block;
        walker_generic<<<grid, block, 0, stream>>>(adj_nodes, adj_offset,
                                                   degrees, choices, out, n, steps);
    }
}

// Round 6
// 119.389 us; speedup vs baseline: 1.1510x; 1.1510x over previous
//
#include <hip/hip_runtime.h>
#include <hip/hip_bf16.h>

// Non-backtracking random walk, 32 steps.
// out = [walks (steps+1,n) ; walk_edges (steps,n)] int32.
//
// R6: R5 regression root-caused: 64B rows grew table to 6.4MB > 4MiB/XCD L2
// (FETCH 84.7MB @2TB/s). Also: the harness's 268MB ws-poison wipes L2+IF$
// every iteration, so gathers were refilling the table via low-MLP cold
// misses (~1TB/s). Fixes:
//  (a) back to 32B rows (16 u16 lo) + separate 200KB hi-bit array: 3.4MB
//      total, L2-resident; chosen+alt always in ONE 64B line.
//  (b) XCD-sliced streaming prefetch at walker start: blockIdx%8 ~ XCD
//      (round-robin dispatch heuristic); each XCD's blocks collectively
//      stream the full table with coalesced uint4 loads -> table lands in
//      all 8 L2s in ~3us instead of ~30us of low-MLP demand misses.
//  (c) 2 chains/thread (R4-proven MLP boost).
// Pack kernel verifies uniform CSR (deg==16, offset==16v, ids<2^17); on
// violation walker takes a fully-general fallback.

#define DEG 16
#define CHAINS 2

__global__ void pack_check_kernel(const int* __restrict__ adj_nodes,
                                  const int* __restrict__ adj_offset,
                                  const int* __restrict__ degrees,
                                  int n,
                                  unsigned int* __restrict__ lo32,   // 8 u32 per row (32B)
                                  unsigned short* __restrict__ hi,   // hbits per node
                                  int* __restrict__ flag) {
    int v = blockIdx.x * blockDim.x + threadIdx.x;
    if (v >= n) return;

    bool bad = (degrees[v] != DEG) || (adj_offset[v] != v * DEG);

    const uint4* row4 = (const uint4*)(adj_nodes + (size_t)v * DEG); // 64B-aligned
    uint4 r[4];
    r[0] = row4[0]; r[1] = row4[1]; r[2] = row4[2]; r[3] = row4[3];
    const unsigned* rr = (const unsigned*)r;

    union { unsigned u32[8]; uint4 v4[2]; } p;
    unsigned hbits = 0;
#pragma unroll
    for (int j = 0; j < 8; ++j) {
        unsigned u0 = rr[2 * j];
        unsigned u1 = rr[2 * j + 1];
        if (u0 >= 131072u || u1 >= 131072u) bad = true;   // needs >17 bits
        p.u32[j] = (u0 & 0xffffu) | ((u1 & 0xffffu) << 16);
        hbits |= ((u0 >> 16) & 1u) << (2 * j);
        hbits |= ((u1 >> 16) & 1u) << (2 * j + 1);
    }
    uint4* dst = (uint4*)(lo32 + (size_t)v * 8);          // 32B row
    dst[0] = p.v4[0];
    dst[1] = p.v4[1];
    hi[v] = (unsigned short)hbits;

    if (bad) atomicOr(flag, 1);
}

template <int STEPS>
__global__ __launch_bounds__(64) void walker_fast2(
    const unsigned short* __restrict__ pk,   // 16 u16 per row (32B stride)
    const unsigned short* __restrict__ hi,   // hbits per node
    const int* __restrict__ choices,
    int* __restrict__ out, int n, int h,
    const int* __restrict__ flag,
    int* __restrict__ sink,
    const int* __restrict__ adj_nodes,
    const int* __restrict__ adj_offset,
    const int* __restrict__ degrees) {

    // ---- XCD-sliced table prefetch (all threads, before any early-out) ----
    {
        int lane = threadIdx.x & 63;
        int g    = blockIdx.x & 7;          // heuristic XCD id
        int s    = (blockIdx.x >> 3);       // slice within this XCD's group
        int nsl  = (gridDim.x + 7) >> 3;    // slices per XCD
        (void)g;
        const uint4* tbl = (const uint4*)pk;
        int total = n >> 1;                 // n*16 u16 = n*32B -> n/2 uint4
        unsigned acc = 0;
        for (int i = s * 64 + lane; i < total; i += nsl * 64) {
            uint4 v = tbl[i];
            acc ^= v.x ^ v.y ^ v.z ^ v.w;
        }
        const uint4* ht = (const uint4*)hi;
        int htotal = n >> 3;                // n u16 -> n/8 uint4
        for (int i = s * 64 + lane; i < htotal; i += nsl * 64) {
            uint4 v = ht[i];
            acc ^= v.x ^ v.y ^ v.z ^ v.w;
        }
        if (acc == 0xDEADBEEFu) *sink = 1;  // keeps loads alive; store harmless
    }

    int t = blockIdx.x * blockDim.x + threadIdx.x;
    if (t >= h) return;

    int* walks      = out;                    // [STEPS+1, n]
    int* walk_edges = out + (STEPS + 1) * n;  // [STEPS, n]

    int w0 = t;
    int w1 = t + h;
    bool has1 = (w1 < n);
    int w1s = has1 ? w1 : w0;

    __builtin_nontemporal_store(w0, &walks[w0]);
    if (has1) __builtin_nontemporal_store(w1, &walks[w1]);

    if (*flag == 0) {
        // ---- fast path: uniform CSR deg=16, 32B rows, 2 chains/thread ----
        int prev0 = -1, cur0 = w0;
        int prev1 = -1, cur1 = w1s;

        static_assert(STEPS % 16 == 0, "");
#pragma unroll 1
        for (int half = 0; half < STEPS / 16; ++half) {
            int c0[16], c1[16];
#pragma unroll
            for (int i = 0; i < 16; ++i) {
                c0[i] = __builtin_nontemporal_load(&choices[(half * 16 + i) * n + w0]);
                c1[i] = __builtin_nontemporal_load(&choices[(half * 16 + i) * n + w1s]);
            }
#pragma unroll
            for (int i = 0; i < 16; ++i) {
                int step = half * 16 + i;
                int ch0 = c0[i], ch1 = c1[i];
                unsigned e0 = ch0 & (DEG - 1);
                unsigned e1 = ch1 & (DEG - 1);
                unsigned a0 = (e0 + 1 + ch0 % (DEG - 1)) & (DEG - 1);
                unsigned a1 = (e1 + 1 + ch1 % (DEG - 1)) & (DEG - 1);

                const unsigned short* r0 = pk + (unsigned)cur0 * 16u;
                const unsigned short* r1 = pk + (unsigned)cur1 * 16u;

                // six independent loads; row pair is one 64B line each
                unsigned l00 = r0[e0];
                unsigned l01 = r0[a0];
                unsigned hb0 = hi[cur0];
                unsigned l10 = r1[e1];
                unsigned l11 = r1[a1];
                unsigned hb1 = hi[cur1];

                int n00 = (int)(l00 | (((hb0 >> e0) & 1u) << 16));
                int n01 = (int)(l01 | (((hb0 >> a0) & 1u) << 16));
                int n10 = (int)(l10 | (((hb1 >> e1) & 1u) << 16));
                int n11 = (int)(l11 | (((hb1 >> a1) & 1u) << 16));

                bool bt0 = (n00 == prev0);
                bool bt1 = (n10 == prev1);
                int nw0 = bt0 ? n01 : n00;
                int nw1 = bt1 ? n11 : n10;
                int ce0 = (cur0 << 4) + (int)(bt0 ? a0 : e0);
                int ce1 = (cur1 << 4) + (int)(bt1 ? a1 : e1);

                __builtin_nontemporal_store(nw0, &walks[(step + 1) * n + w0]);
                __builtin_nontemporal_store(ce0, &walk_edges[step * n + w0]);
                if (has1) {
                    __builtin_nontemporal_store(nw1, &walks[(step + 1) * n + w1]);
                    __builtin_nontemporal_store(ce1, &walk_edges[step * n + w1]);
                }
                prev0 = cur0; cur0 = nw0;
                prev1 = cur1; cur1 = nw1;
            }
        }
    } else {
        // ---- general fallback: 2 dependent gathers/step ----
        for (int k = 0; k < 2; ++k) {
            int w = (k == 0) ? w0 : w1;
            if (w >= n) break;
            int prev = -1, cur = w;
            for (int i = 0; i < STEPS; ++i) {
                int chv = choices[i * n + w];
                int deg = degrees[cur];
                int off = adj_offset[cur];
                int nb  = deg - 1 > 1 ? deg - 1 : 1;

                int e      = chv % deg;
                int chosen = off + e;
                int alt    = off + (e + 1 + chv % nb) % deg;

                int nv0 = adj_nodes[chosen];
                int nv1 = adj_nodes[alt];

                bool bt = (nv0 == prev);
                int nw  = bt ? nv1 : nv0;
                walks[(i + 1) * n + w] = nw;
                walk_edges[i * n + w]  = bt ? alt : chosen;
                prev = cur;
                cur  = nw;
            }
        }
    }
}

__global__ __launch_bounds__(256) void walker_generic(
    const int* __restrict__ adj_nodes,
    const int* __restrict__ adj_offset,
    const int* __restrict__ degrees,
    const int* __restrict__ choices,
    int* __restrict__ out, int n, int steps) {

    int w = blockIdx.x * blockDim.x + threadIdx.x;
    if (w >= n) return;

    int* walks      = out;
    int* walk_edges = out + (steps + 1) * n;
    walks[w] = w;

    int prev = -1, cur = w;
    for (int i = 0; i < steps; ++i) {
        int chv = choices[i * n + w];
        int deg = degrees[cur];
        int off = adj_offset[cur];
        int nb  = deg - 1 > 1 ? deg - 1 : 1;

        int e      = chv % deg;
        int chosen = off + e;
        int alt    = off + (e + 1 + chv % nb) % deg;

        int nv0 = adj_nodes[chosen];
        int nv1 = adj_nodes[alt];

        bool bt = (nv0 == prev);
        int nw  = bt ? nv1 : nv0;
        walks[(i + 1) * n + w] = nw;
        walk_edges[i * n + w]  = bt ? alt : chosen;
        prev = cur;
        cur  = nw;
    }
}

extern "C" void kernel_launch(void* const* d_in, const int* in_sizes, int n_in,
                              void* d_out, int out_size, void* d_ws, size_t ws_size,
                              hipStream_t stream) {
    // inputs: 0=x (unused), 1=adj_nodes, 2=adj_offset, 3=degrees, 4=choices
    const int* adj_nodes  = (const int*)d_in[1];
    const int* adj_offset = (const int*)d_in[2];
    const int* degrees    = (const int*)d_in[3];
    const int* choices    = (const int*)d_in[4];
    int* out = (int*)d_out;

    int n     = in_sizes[2];
    int steps = in_sizes[4] / n;

    // ws layout: [0,4) flag | [8,12) sink | [64, 64+32n) lo rows | aligned hi u16[n]
    size_t lo_off = 64;
    size_t lo_bytes = (size_t)n * 32;
    size_t hi_off = lo_off + ((lo_bytes + 63) & ~(size_t)63);
    size_t need   = hi_off + (size_t)n * 2;

    if (steps == 32 && ws_size >= need) {
        int* flag = (int*)d_ws;
        int* sink = (int*)((char*)d_ws + 8);
        unsigned int*   lo32 = (unsigned int*)((char*)d_ws + lo_off);
        unsigned short* pk   = (unsigned short*)lo32;
        unsigned short* hi   = (unsigned short*)((char*)d_ws + hi_off);

        hipMemsetAsync(flag, 0, sizeof(int), stream);
        int pb = 256, pg = (n + pb - 1) / pb;
        pack_check_kernel<<<pg, pb, 0, stream>>>(adj_nodes, adj_offset, degrees,
                                                 n, lo32, hi, flag);
        int h  = (n + CHAINS - 1) / CHAINS;
        int wb = 64, wg = (h + wb - 1) / wb;
        walker_fast2<32><<<wg, wb, 0, stream>>>(pk, hi, choices, out, n, h, flag,
                                                sink, adj_nodes, adj_offset, degrees);
    } else {
        int block = 256, grid = (n + block - 1) / block;
        walker_generic<<<grid, block, 0, stream>>>(adj_nodes, adj_offset,
                                                   degrees, choices, out, n, steps);
    }
}